// Round 6
// baseline (240.299 us; speedup 1.0000x reference)
//
#include <hip/hip_runtime.h>

#define LEN 128
#define NB 32
#define NC 16
#define NU 16
#define NK 5
#define KC 80          // (k,c) pairs, kc = k*16+c
#define KCP 96         // padded K for stage2
#define LUN 80

typedef unsigned int uint32;
typedef unsigned short u16;
typedef __attribute__((ext_vector_type(8))) short bf16x8;
typedef __attribute__((ext_vector_type(4))) float f32x4;

#define MFMA(a, b, c) __builtin_amdgcn_mfma_f32_16x16x32_bf16(a, b, c, 0, 0, 0)

static __device__ inline u16 f2bf(float f) {
    union { float f; uint32 u; } v; v.f = f;
    uint32 u = v.u;
    return (u16)((u + 0x7fffu + ((u >> 16) & 1u)) >> 16);   // RNE
}
static __device__ inline uint32 pkbf(float a, float b) {    // low=a, high=b
    return (uint32)f2bf(a) | ((uint32)f2bf(b) << 16);
}
static __device__ inline bf16x8 frag16(const void* p) { return *(const bf16x8*)p; }
static __device__ inline bf16x8 frag4(const uint32* p) {    // 4B-aligned, contiguous
    union { uint32 u[4]; bf16x8 v; } t;
    t.u[0] = p[0]; t.u[1] = p[1]; t.u[2] = p[2]; t.u[3] = p[3];
    return t.v;
}

// ---------------- k0_all: blocks 0..511 transpose x -> xT; blocks 512+ build tables
// xT[bc][w][h2] bf16-pair dwords; cheb1T[k*128+p][h]; cheb2T[q][l*128+w]; coefTT[lu][kc] (K-pad 96)
__global__ __launch_bounds__(256) void k0_all(const float* __restrict__ x,
                                              const float* __restrict__ coefs,
                                              const float* __restrict__ cheb1,
                                              const float* __restrict__ cheb2,
                                              uint32* __restrict__ xT,
                                              u16* __restrict__ cheb1T,
                                              u16* __restrict__ cheb2T,
                                              u16* __restrict__ coefTT) {
    __shared__ float Ls[32][131];
    const int blk = blockIdx.x;
    const int tid = threadIdx.x;
    if (blk < 512) {
        const int bc = blk;
        const float* xp = x + (size_t)bc * (LEN * LEN);
        uint32* op = xT + (size_t)bc * (LEN * 64);
        for (int slab = 0; slab < 4; ++slab) {
            __syncthreads();
            {   // stage 32 h-rows x 128 w, coalesced float4
                int h = tid >> 3, wq = tid & 7;
                const float* src = xp + (size_t)(slab * 32 + h) * LEN + wq * 16;
                #pragma unroll
                for (int j = 0; j < 4; ++j) {
                    float4 v = *(const float4*)(src + 4 * j);
                    Ls[h][wq * 16 + 4 * j + 0] = v.x;
                    Ls[h][wq * 16 + 4 * j + 1] = v.y;
                    Ls[h][wq * 16 + 4 * j + 2] = v.z;
                    Ls[h][wq * 16 + 4 * j + 3] = v.w;
                }
            }
            __syncthreads();
            {   // write transposed: lanes h2-contiguous -> 64B runs
                int h2 = tid & 15, wg = tid >> 4;
                #pragma unroll
                for (int ww = 0; ww < 8; ++ww) {
                    int w = wg * 8 + ww;
                    op[(size_t)w * 64 + slab * 16 + h2] = pkbf(Ls[2 * h2][w], Ls[2 * h2 + 1][w]);
                }
            }
        }
    } else {
        int i = (blk - 512) * 256 + tid;
        if (i < 81920) {
            int r = i >> 7, h = i & 127;
            int k = r >> 7, p = r & 127;
            cheb1T[i] = f2bf(cheb1[(k * LEN + h) * LEN + p]);
        } else if (i < 163840) {
            int j = i - 81920;
            int q = j / 640, t = j % 640;
            int l = t >> 7, w = t & 127;
            cheb2T[j] = f2bf(cheb2[(l * LEN + w) * LEN + q]);
        } else if (i < 171520) {
            int j = i - 163840;
            int lu = j / KCP, kc = j % KCP;
            int l = lu >> 4, u = lu & 15, k = kc >> 4, c = kc & 15;
            coefTT[j] = (kc < KC) ? f2bf(coefs[((k * NK + l) * NC + c) * NU + u]) : (u16)0;
        }
    }
}

// ---------------- k1: t1[bl][p][k][c][w] = sum_h cheb1[k][h][p]*x[b][c][h][w]
// LDS-free: A = xT rows (M=w), B = cheb1T rows (N=kp window of 160), K=128 h.
// grid (8, 4, 2*cb): kpw=y stride 8 => all kpw of (c,bl) share an XCD for xT reuse
__global__ __launch_bounds__(256, 3) void k1_mfma(const uint32* __restrict__ xT,
                                                  const uint32* __restrict__ cheb1T,
                                                  u16* __restrict__ t1, int b0) {
    const int kpw = blockIdx.y, zz = blockIdx.z;
    const int c = blockIdx.x + 8 * (zz & 1);
    const int bl = zz >> 1;
    const int tid = threadIdx.x;
    const int lane = tid & 63, wave = tid >> 6;
    const int m16 = lane & 15, g = lane >> 4;
    const int wm = wave >> 1, wn = wave & 1;

    const uint32* xrow = xT + (size_t)((b0 + bl) * NC + c) * (LEN * 64);

    f32x4 acc[4][5];
    #pragma unroll
    for (int mi = 0; mi < 4; ++mi)
        #pragma unroll
        for (int ni = 0; ni < 5; ++ni) acc[mi][ni] = (f32x4)0.f;

    #pragma unroll
    for (int ks = 0; ks < 4; ++ks) {
        bf16x8 Af[4], Bf[5];
        #pragma unroll
        for (int mi = 0; mi < 4; ++mi)
            Af[mi] = frag16(xrow + (size_t)(wm * 64 + mi * 16 + m16) * 64 + ks * 16 + g * 4);
        #pragma unroll
        for (int ni = 0; ni < 5; ++ni)
            Bf[ni] = frag16(cheb1T + (size_t)(kpw * 160 + wn * 80 + ni * 16 + m16) * 64 + ks * 16 + g * 4);
        #pragma unroll
        for (int mi = 0; mi < 4; ++mi)
            #pragma unroll
            for (int ni = 0; ni < 5; ++ni)
                acc[mi][ni] = MFMA(Af[mi], Bf[ni], acc[mi][ni]);
    }

    #pragma unroll
    for (int ni = 0; ni < 5; ++ni) {
        int kp = kpw * 160 + wn * 80 + ni * 16 + m16;
        int k = kp >> 7, p = kp & 127;
        size_t base = (((size_t)(bl * LEN + p) * NK + k) * NC + c) * LEN;
        #pragma unroll
        for (int mi = 0; mi < 4; ++mi) {
            int w0 = wm * 64 + mi * 16 + g * 4;
            uint2 d;
            d.x = pkbf(acc[mi][ni][0], acc[mi][ni][1]);
            d.y = pkbf(acc[mi][ni][2], acc[mi][ni][3]);
            *(uint2*)(t1 + base + w0) = d;
        }
    }
}

// ---------------- k2: per (p, bl) block — 1 p-slice, 27KB LDS, high occupancy
// stage2: s[w][lu] = Ts[w][kc] x coefTT[lu][kc]  (M=128, N=80, K=96)
// stage3: out[u][q] = A3[u][l*128+w] x cheb2T[q][l*128+w]  (M=16, N=128, K=640)
__global__ __launch_bounds__(256, 5) void k2_mfma(const u16* __restrict__ t1,
                                                  const u16* __restrict__ coefTT,
                                                  const u16* __restrict__ cheb2T,
                                                  float* __restrict__ out, int b0) {
    __shared__ uint32 sm[128 * 53];   // Ts [w][kc2] stride 53 (27136 B); A3 [u][327] aliases
    const int p = blockIdx.x, bl = blockIdx.y, b = b0 + bl;
    const int tid = threadIdx.x;
    const int lane = tid & 63, wave = tid >> 6;
    const int n16 = lane & 15, g = lane >> 4;

    // stage t1 slice (80 rows x 64 dw) -> Ts[w][kc-pairs]
    {
        const uint32* t1u = (const uint32*)(t1 + (size_t)(bl * LEN + p) * (KC * LEN));
        #pragma unroll
        for (int i = 0; i < 3; ++i) {
            int it = tid + i * 256;          // 0..639
            if (it < 640) {
                int kc2 = it >> 4, wq = it & 15;
                const uint32* src = t1u + kc2 * 128 + wq * 4;
                uint4 Av = *(const uint4*)(src);
                uint4 Bv = *(const uint4*)(src + 64);
                uint32* dst = sm + (wq * 8) * 53 + kc2;
                const uint32* av = (const uint32*)&Av;
                const uint32* bv = (const uint32*)&Bv;
                #pragma unroll
                for (int j = 0; j < 4; ++j) {
                    dst[(2 * j) * 53]     = (av[j] & 0xffffu) | (bv[j] << 16);
                    dst[(2 * j + 1) * 53] = (av[j] >> 16) | (bv[j] & 0xffff0000u);
                }
            }
        }
        for (int j = tid; j < 1024; j += 256) {   // zero K-pad kc2 40..47
            int row = j >> 3, d = 40 + (j & 7);
            sm[row * 53 + d] = 0;
        }
    }
    __syncthreads();

    // stage2: waves split w (4 x 32); per wave 2 m-tiles x 5 n-tiles
    f32x4 acc[2][5];
    #pragma unroll
    for (int mi = 0; mi < 2; ++mi)
        #pragma unroll
        for (int n = 0; n < 5; ++n) acc[mi][n] = (f32x4)0.f;

    #pragma unroll
    for (int ks = 0; ks < 3; ++ks) {
        bf16x8 Af[2], Bf[5];
        #pragma unroll
        for (int mi = 0; mi < 2; ++mi)
            Af[mi] = frag4(sm + (wave * 32 + mi * 16 + n16) * 53 + ks * 16 + g * 4);
        #pragma unroll
        for (int n = 0; n < 5; ++n)
            Bf[n] = frag16(coefTT + (size_t)(n * 16 + n16) * KCP + ks * 32 + g * 8);
        #pragma unroll
        for (int mi = 0; mi < 2; ++mi)
            #pragma unroll
            for (int n = 0; n < 5; ++n)
                acc[mi][n] = MFMA(Af[mi], Bf[n], acc[mi][n]);
    }
    __syncthreads();   // Ts reads done; A3 overwrites

    // s -> A3 bf16 A-layout: row u (stride 327 dw => 2-way max on reads), col (l*128+w)/2
    #pragma unroll
    for (int mi = 0; mi < 2; ++mi)
        #pragma unroll
        for (int n = 0; n < 5; ++n) {
            int lu = n * 16 + n16, l = lu >> 4, u = lu & 15;
            int w0 = wave * 32 + mi * 16 + g * 4;
            uint32* d = sm + u * 327 + l * 64 + (w0 >> 1);
            d[0] = pkbf(acc[mi][n][0], acc[mi][n][1]);
            d[1] = pkbf(acc[mi][n][2], acc[mi][n][3]);
        }
    __syncthreads();

    // stage3: M=16 (u), wave owns 32 q, K=640
    f32x4 c3[2];
    c3[0] = (f32x4)0.f; c3[1] = (f32x4)0.f;
    #pragma unroll 5
    for (int ks = 0; ks < 20; ++ks) {
        bf16x8 Af2 = frag4(sm + n16 * 327 + ks * 16 + g * 4);
        #pragma unroll
        for (int nt = 0; nt < 2; ++nt) {
            bf16x8 Bf2 = frag16(cheb2T + (size_t)(wave * 32 + nt * 16 + n16) * 640 + ks * 32 + g * 8);
            c3[nt] = MFMA(Af2, Bf2, c3[nt]);
        }
    }

    #pragma unroll
    for (int nt = 0; nt < 2; ++nt)
        #pragma unroll
        for (int r = 0; r < 4; ++r) {
            int u = g * 4 + r;
            int q = wave * 32 + nt * 16 + n16;
            out[(((size_t)(b * NU + u)) * LEN + p) * LEN + q] = c3[nt][r];
        }
}

extern "C" void kernel_launch(void* const* d_in, const int* in_sizes, int n_in,
                              void* d_out, int out_size, void* d_ws, size_t ws_size,
                              hipStream_t stream) {
    const float* x     = (const float*)d_in[0];
    const float* coefs = (const float*)d_in[1];
    const float* cheb1 = (const float*)d_in[2];
    const float* cheb2 = (const float*)d_in[3];
    float* out = (float*)d_out;

    const size_t xT_bytes = (size_t)NB * NC * LEN * 64 * 4;   // 16.78 MB
    const size_t aux_bytes = xT_bytes + 163840 + 163840 + 15360;
    size_t aux_off = (ws_size > aux_bytes + 256) ? ((ws_size - aux_bytes) & ~(size_t)255) : 0;

    uint32* xT  = (uint32*)((char*)d_ws + aux_off);
    u16* cheb1T = (u16*)((char*)xT + xT_bytes);
    u16* cheb2T = cheb1T + 81920;
    u16* coefTT = cheb2T + 81920;
    u16* t1 = (u16*)d_ws;

    const size_t per_b = (size_t)NK * NC * LEN * LEN * sizeof(u16);   // 2.62 MB
    int chunk = (int)(aux_off / per_b);
    if (chunk < 1) chunk = 1;
    if (chunk > NB) chunk = NB;

    hipLaunchKernelGGL(k0_all, dim3(512 + (171520 + 255) / 256), dim3(256), 0, stream,
                       x, coefs, cheb1, cheb2, xT, cheb1T, cheb2T, coefTT);

    for (int b0 = 0; b0 < NB; b0 += chunk) {
        int cb = (NB - b0 < chunk) ? (NB - b0) : chunk;
        hipLaunchKernelGGL(k1_mfma, dim3(8, 4, 2 * cb), dim3(256), 0, stream,
                           xT, (const uint32*)cheb1T, t1, b0);
        hipLaunchKernelGGL(k2_mfma, dim3(LEN, cb), dim3(256), 0, stream,
                           t1, coefTT, cheb2T, out, b0);
    }
}

// Round 7
// 229.410 us; speedup vs baseline: 1.0475x; 1.0475x over previous
//
#include <hip/hip_runtime.h>

#define LEN 128
#define NB 32
#define NC 16
#define NU 16
#define NK 5
#define KC 80          // (k,c) pairs, kc = k*16+c
#define KCP 96         // padded K for stage2
#define LUN 80

typedef unsigned int uint32;
typedef unsigned short u16;
typedef __attribute__((ext_vector_type(8))) short bf16x8;
typedef __attribute__((ext_vector_type(4))) float f32x4;

#define MFMA(a, b, c) __builtin_amdgcn_mfma_f32_16x16x32_bf16(a, b, c, 0, 0, 0)

static __device__ inline u16 f2bf(float f) {
    union { float f; uint32 u; } v; v.f = f;
    uint32 u = v.u;
    return (u16)((u + 0x7fffu + ((u >> 16) & 1u)) >> 16);   // RNE
}
static __device__ inline uint32 pkbf(float a, float b) {    // low=a, high=b
    return (uint32)f2bf(a) | ((uint32)f2bf(b) << 16);
}
static __device__ inline bf16x8 frag16(const void* p) { return *(const bf16x8*)p; }
static __device__ inline bf16x8 frag4(const uint32* p) {    // 4B-aligned, contiguous
    union { uint32 u[4]; bf16x8 v; } t;
    t.u[0] = p[0]; t.u[1] = p[1]; t.u[2] = p[2]; t.u[3] = p[3];
    return t.v;
}

// ---------------- k0_all: blocks 0..511 transpose x -> xT; blocks 512+ build tables
__global__ __launch_bounds__(256) void k0_all(const float* __restrict__ x,
                                              const float* __restrict__ coefs,
                                              const float* __restrict__ cheb1,
                                              const float* __restrict__ cheb2,
                                              uint32* __restrict__ xT,
                                              u16* __restrict__ cheb1T,
                                              u16* __restrict__ cheb2T,
                                              u16* __restrict__ coefTT) {
    __shared__ float Ls[32][131];
    const int blk = blockIdx.x;
    const int tid = threadIdx.x;
    if (blk < 512) {
        const int bc = blk;
        const float* xp = x + (size_t)bc * (LEN * LEN);
        uint32* op = xT + (size_t)bc * (LEN * 64);
        for (int slab = 0; slab < 4; ++slab) {
            __syncthreads();
            {
                int h = tid >> 3, wq = tid & 7;
                const float* src = xp + (size_t)(slab * 32 + h) * LEN + wq * 16;
                #pragma unroll
                for (int j = 0; j < 4; ++j) {
                    float4 v = *(const float4*)(src + 4 * j);
                    Ls[h][wq * 16 + 4 * j + 0] = v.x;
                    Ls[h][wq * 16 + 4 * j + 1] = v.y;
                    Ls[h][wq * 16 + 4 * j + 2] = v.z;
                    Ls[h][wq * 16 + 4 * j + 3] = v.w;
                }
            }
            __syncthreads();
            {
                int h2 = tid & 15, wg = tid >> 4;
                #pragma unroll
                for (int ww = 0; ww < 8; ++ww) {
                    int w = wg * 8 + ww;
                    op[(size_t)w * 64 + slab * 16 + h2] = pkbf(Ls[2 * h2][w], Ls[2 * h2 + 1][w]);
                }
            }
        }
    } else {
        int i = (blk - 512) * 256 + tid;
        if (i < 81920) {
            int r = i >> 7, h = i & 127;
            int k = r >> 7, p = r & 127;
            cheb1T[i] = f2bf(cheb1[(k * LEN + h) * LEN + p]);
        } else if (i < 163840) {
            int j = i - 81920;
            int q = j / 640, t = j % 640;
            int l = t >> 7, w = t & 127;
            cheb2T[j] = f2bf(cheb2[(l * LEN + w) * LEN + q]);
        } else if (i < 171520) {
            int j = i - 163840;
            int lu = j / KCP, kc = j % KCP;
            int l = lu >> 4, u = lu & 15, k = kc >> 4, c = kc & 15;
            coefTT[j] = (kc < KC) ? f2bf(coefs[((k * NK + l) * NC + c) * NU + u]) : (u16)0;
        }
    }
}

// ---------------- k1 v3: block = (c, kp-half, bl); Xs in LDS from xT (coalesced copy),
// A-frags = ds_read_b128; B-frags = cheb1T from L2. 2 passes x (M=128w x N=160kp), K=128h.
__global__ __launch_bounds__(256, 4) void k1_mfma(const uint32* __restrict__ xT,
                                                  const uint32* __restrict__ cheb1T,
                                                  u16* __restrict__ t1, int b0) {
    __shared__ uint32 Xs[128 * 68];   // 34816 B; rows 16B-aligned, 2-way max conflicts
    const int c = blockIdx.x, half = blockIdx.y, bl = blockIdx.z;
    const int b = b0 + bl;
    const int tid = threadIdx.x;
    const int lane = tid & 63, wave = tid >> 6;
    const int m16 = lane & 15, g = lane >> 4;
    const int wm = wave >> 1, wn = wave & 1;

    // stage Xs: straight uint4 copy of xT slice (rows 64 dw -> stride 68)
    {
        const uint32* xrow = xT + (size_t)(b * NC + c) * (LEN * 64);
        #pragma unroll
        for (int i = 0; i < 8; ++i) {
            int fi = tid + i * 256;            // 0..2047 uint4
            int row = fi >> 4, col4 = (fi & 15) * 4;
            *(uint4*)(Xs + row * 68 + col4) = *(const uint4*)(xrow + row * 64 + col4);
        }
    }
    __syncthreads();

    for (int pass = 0; pass < 2; ++pass) {
        const int kpbase = half * 320 + pass * 160;

        f32x4 acc[4][5];
        #pragma unroll
        for (int mi = 0; mi < 4; ++mi)
            #pragma unroll
            for (int ni = 0; ni < 5; ++ni) acc[mi][ni] = (f32x4)0.f;

        #pragma unroll
        for (int ks = 0; ks < 4; ++ks) {
            bf16x8 Af[4], Bf[5];
            #pragma unroll
            for (int mi = 0; mi < 4; ++mi)
                Af[mi] = frag16(Xs + (wm * 64 + mi * 16 + m16) * 68 + ks * 16 + g * 4);
            #pragma unroll
            for (int ni = 0; ni < 5; ++ni)
                Bf[ni] = frag16(cheb1T + (size_t)(kpbase + wn * 80 + ni * 16 + m16) * 64 + ks * 16 + g * 4);
            #pragma unroll
            for (int mi = 0; mi < 4; ++mi)
                #pragma unroll
                for (int ni = 0; ni < 5; ++ni)
                    acc[mi][ni] = MFMA(Af[mi], Bf[ni], acc[mi][ni]);
        }

        // epilogue: lane holds 4 consecutive w at fixed kp -> uint2 stores
        #pragma unroll
        for (int ni = 0; ni < 5; ++ni) {
            int kp = kpbase + wn * 80 + ni * 16 + m16;
            int k = kp >> 7, p = kp & 127;
            size_t base = (((size_t)(bl * LEN + p) * NK + k) * NC + c) * LEN;
            #pragma unroll
            for (int mi = 0; mi < 4; ++mi) {
                int w0 = wm * 64 + mi * 16 + g * 4;
                uint2 d;
                d.x = pkbf(acc[mi][ni][0], acc[mi][ni][1]);
                d.y = pkbf(acc[mi][ni][2], acc[mi][ni][3]);
                *(uint2*)(t1 + base + w0) = d;
            }
        }
    }
}

// ---------------- k2: R5 version verbatim (2 p-slices, stride-53 Ts, A3 stride 326)
__global__ __launch_bounds__(256, 2) void k2_mfma(const u16* __restrict__ t1,
                                                  const u16* __restrict__ coefTT,
                                                  const u16* __restrict__ cheb2T,
                                                  float* __restrict__ out, int b0) {
    __shared__ uint32 sm[256 * 53];
    const int pg = blockIdx.x, bl = blockIdx.y, b = b0 + bl;
    const int tid = threadIdx.x;
    const int lane = tid & 63, wave = tid >> 6;
    const int n16 = lane & 15, g = lane >> 4;
    const int wp = wave >> 1, ww = wave & 1;

    {
        const uint32* t1u = (const uint32*)(t1 + (size_t)(bl * LEN + 2 * pg) * (KC * LEN));
        #pragma unroll
        for (int i = 0; i < 5; ++i) {
            int it = tid + i * 256;
            int p_i = (it >= 640) ? 1 : 0;
            int rem = it - 640 * p_i;
            int kc2 = rem >> 4, wq = rem & 15;
            const uint32* src = t1u + p_i * 5120 + kc2 * 128 + wq * 4;
            uint4 Av = *(const uint4*)(src);
            uint4 Bv = *(const uint4*)(src + 64);
            uint32* dst = sm + (p_i * 128 + wq * 8) * 53 + kc2;
            const uint32* av = (const uint32*)&Av;
            const uint32* bv = (const uint32*)&Bv;
            #pragma unroll
            for (int j = 0; j < 4; ++j) {
                dst[(2 * j) * 53]     = (av[j] & 0xffffu) | (bv[j] << 16);
                dst[(2 * j + 1) * 53] = (av[j] >> 16) | (bv[j] & 0xffff0000u);
            }
        }
        for (int j = tid; j < 2048; j += 256) {
            int row = j >> 3, d = 40 + (j & 7);
            sm[row * 53 + d] = 0;
        }
    }
    __syncthreads();

    f32x4 acc[4][5];
    #pragma unroll
    for (int mi = 0; mi < 4; ++mi)
        #pragma unroll
        for (int n = 0; n < 5; ++n) acc[mi][n] = (f32x4)0.f;

    #pragma unroll
    for (int ks = 0; ks < 3; ++ks) {
        bf16x8 Af[4], Bf[5];
        #pragma unroll
        for (int mi = 0; mi < 4; ++mi)
            Af[mi] = frag4(sm + (wp * 128 + ww * 64 + mi * 16 + n16) * 53 + ks * 16 + g * 4);
        #pragma unroll
        for (int n = 0; n < 5; ++n)
            Bf[n] = frag16(coefTT + (size_t)(n * 16 + n16) * KCP + ks * 32 + g * 8);
        #pragma unroll
        for (int mi = 0; mi < 4; ++mi)
            #pragma unroll
            for (int n = 0; n < 5; ++n)
                acc[mi][n] = MFMA(Af[mi], Bf[n], acc[mi][n]);
    }
    __syncthreads();

    {
        uint32* A3 = sm;
        #pragma unroll
        for (int mi = 0; mi < 4; ++mi)
            #pragma unroll
            for (int n = 0; n < 5; ++n) {
                int lu = n * 16 + n16, l = lu >> 4, u = lu & 15;
                int w0 = ww * 64 + mi * 16 + g * 4;
                uint32* d = A3 + (wp * 16 + u) * 326 + l * 64 + (w0 >> 1);
                d[0] = pkbf(acc[mi][n][0], acc[mi][n][1]);
                d[1] = pkbf(acc[mi][n][2], acc[mi][n][3]);
            }
    }
    __syncthreads();

    const uint32* A3 = sm;
    f32x4 c3[2][2];
    c3[0][0] = (f32x4)0.f; c3[0][1] = (f32x4)0.f;
    c3[1][0] = (f32x4)0.f; c3[1][1] = (f32x4)0.f;
    #pragma unroll 4
    for (int ks = 0; ks < 20; ++ks) {
        bf16x8 Af2[2], Bf2[2];
        #pragma unroll
        for (int mi = 0; mi < 2; ++mi)
            Af2[mi] = frag4(A3 + (mi * 16 + n16) * 326 + ks * 16 + g * 4);
        #pragma unroll
        for (int nt = 0; nt < 2; ++nt)
            Bf2[nt] = frag16(cheb2T + (size_t)(wave * 32 + nt * 16 + n16) * 640 + ks * 32 + g * 8);
        #pragma unroll
        for (int mi = 0; mi < 2; ++mi)
            #pragma unroll
            for (int nt = 0; nt < 2; ++nt)
                c3[mi][nt] = MFMA(Af2[mi], Bf2[nt], c3[mi][nt]);
    }

    #pragma unroll
    for (int mi = 0; mi < 2; ++mi)
        #pragma unroll
        for (int nt = 0; nt < 2; ++nt)
            #pragma unroll
            for (int r = 0; r < 4; ++r) {
                int u = g * 4 + r;
                int q = wave * 32 + nt * 16 + n16;
                out[(((size_t)(b * NU + u)) * LEN + (2 * pg + mi)) * LEN + q] = c3[mi][nt][r];
            }
}

extern "C" void kernel_launch(void* const* d_in, const int* in_sizes, int n_in,
                              void* d_out, int out_size, void* d_ws, size_t ws_size,
                              hipStream_t stream) {
    const float* x     = (const float*)d_in[0];
    const float* coefs = (const float*)d_in[1];
    const float* cheb1 = (const float*)d_in[2];
    const float* cheb2 = (const float*)d_in[3];
    float* out = (float*)d_out;

    const size_t xT_bytes = (size_t)NB * NC * LEN * 64 * 4;   // 16.78 MB
    const size_t aux_bytes = xT_bytes + 163840 + 163840 + 15360;
    size_t aux_off = (ws_size > aux_bytes + 256) ? ((ws_size - aux_bytes) & ~(size_t)255) : 0;

    uint32* xT  = (uint32*)((char*)d_ws + aux_off);
    u16* cheb1T = (u16*)((char*)xT + xT_bytes);
    u16* cheb2T = cheb1T + 81920;
    u16* coefTT = cheb2T + 81920;
    u16* t1 = (u16*)d_ws;

    const size_t per_b = (size_t)NK * NC * LEN * LEN * sizeof(u16);   // 2.62 MB
    int chunk = (int)(aux_off / per_b);
    if (chunk < 1) chunk = 1;
    if (chunk > NB) chunk = NB;

    hipLaunchKernelGGL(k0_all, dim3(512 + (171520 + 255) / 256), dim3(256), 0, stream,
                       x, coefs, cheb1, cheb2, xT, cheb1T, cheb2T, coefTT);

    for (int b0 = 0; b0 < NB; b0 += chunk) {
        int cb = (NB - b0 < chunk) ? (NB - b0) : chunk;
        hipLaunchKernelGGL(k1_mfma, dim3(NC, 2, cb), dim3(256), 0, stream,
                           xT, (const uint32*)cheb1T, t1, b0);
        hipLaunchKernelGGL(k2_mfma, dim3(64, cb), dim3(256), 0, stream,
                           t1, coefTT, cheb2T, out, b0);
    }
}